// Round 5
// baseline (11.803 us; speedup 1.0000x reference)
//
#include <hip/hip_runtime.h>

// out[b] = sum_{distinct v in x[:,b]} W[v] + b_lut[0] + bias[0]
//   x: (200, 1024) int32, W: (100000,) f32, out: (1024,) f32
//
// R5 = R4 with 2 columns per block (512 blocks x 512 threads), still
// 1 token/thread (max TLP). Tests whether per-workgroup fixed cost
// (dispatch + clear + barriers) is a component of the ~9.6 us plateau.

#define VSIZE     100000
#define LENGTH    200
#define BATCH     1024
#define HASH_SIZE 1024
#define EMPTY     0xFFFFFFFFu   // tokens < 100000 never collide with sentinel

__global__ __launch_bounds__(512) void LR2_kernel(
    const int* __restrict__ x,
    const float* __restrict__ W,
    const float* __restrict__ b_lut,
    const float* __restrict__ bias,
    float* __restrict__ out)
{
    __shared__ unsigned ht[2][HASH_SIZE];
    __shared__ float    wsum[8];

    const int t   = threadIdx.x;
    const int col = t >> 8;          // 0 or 1
    const int tt  = t & 255;         // thread within column
    const int b   = blockIdx.x * 2 + col;

    // Long-latency loads first: token gather, speculative W[tok].
    unsigned tok = EMPTY;
    float    w   = 0.0f;
    if (tt < LENGTH) {
        tok = (unsigned)x[tt * BATCH + b];
        w   = W[tok];                // overlaps clear + sync + CAS
    }
    const float tail = b_lut[0] + bias[0];

    // Clear both tables: 2048 words = 512 uint4, one per thread.
    ((uint4*)&ht[0][0])[t] = make_uint4(EMPTY, EMPTY, EMPTY, EMPTY);
    __syncthreads();

    float contrib = 0.0f;
    if (tt < LENGTH) {
        unsigned h = (tok * 2654435761u) >> 22;  // top 10 bits
        for (;;) {
            unsigned old = atomicCAS(&ht[col][h], EMPTY, tok);
            if (old == EMPTY) { contrib = w; break; }  // first occurrence
            if (old == tok) break;                     // duplicate
            h = (h + 1) & (HASH_SIZE - 1);
        }
    }

    // Each wave lies entirely within one column (4 waves/column).
    for (int off = 32; off > 0; off >>= 1)
        contrib += __shfl_down(contrib, off, 64);

    const int wave = t >> 6;                 // 0..7
    if ((t & 63) == 0) wsum[wave] = contrib;
    __syncthreads();

    if (tt == 0) {                           // t == 0 and t == 256
        const int wb = col * 4;
        out[b] = wsum[wb] + wsum[wb + 1] + wsum[wb + 2] + wsum[wb + 3] + tail;
    }
}

extern "C" void kernel_launch(void* const* d_in, const int* in_sizes, int n_in,
                              void* d_out, int out_size, void* d_ws, size_t ws_size,
                              hipStream_t stream) {
    const int*   x     = (const int*)d_in[0];
    const float* W     = (const float*)d_in[1];
    const float* b_lut = (const float*)d_in[2];
    const float* bias  = (const float*)d_in[3];
    float*       out   = (float*)d_out;

    LR2_kernel<<<BATCH / 2, 512, 0, stream>>>(x, W, b_lut, bias, out);
}

// Round 6
// 9.655 us; speedup vs baseline: 1.2225x; 1.2225x over previous
//
#include <hip/hip_runtime.h>

// out[b] = sum_{distinct v in x[:,b]} W[v] + b_lut[0] + bias[0]
//   x: (200, 1024) int32, W: (100000,) f32, out: (1024,) f32
//
// R6: barrier-free variant. One WAVE (64 threads) per column, 1024 blocks.
// Each lane owns rows {lane, lane+64, lane+128} (+192+lane for lane<8),
// i.e. 3-4 tokens with full ILP. Dedup via per-block 1024-slot LDS hash.
// No __syncthreads anywhere: single-wave lockstep + in-order DS pipe make
// clear -> CAS ordering safe; reduction is pure shuffles.

#define VSIZE     100000
#define LENGTH    200
#define BATCH     1024
#define HASH_SIZE 1024
#define EMPTY     0xFFFFFFFFu   // tokens < 100000 never collide with sentinel

__global__ __launch_bounds__(64) void LR2_kernel(
    const int* __restrict__ x,
    const float* __restrict__ W,
    const float* __restrict__ b_lut,
    const float* __restrict__ bias,
    float* __restrict__ out)
{
    __shared__ unsigned ht[HASH_SIZE];

    const int b    = blockIdx.x;
    const int lane = threadIdx.x;          // 0..63, one wave

    // Tokens per lane: rows lane, lane+64, lane+128, and lane+192 if lane<8.
    const int ntok = (lane < (LENGTH - 192)) ? 4 : 3;

    // Issue all long-latency loads first, fully independent (ILP).
    unsigned tok[4];
    float    w[4];
    #pragma unroll
    for (int k = 0; k < 4; ++k) {
        tok[k] = EMPTY;
        w[k]   = 0.0f;
        if (k < ntok) tok[k] = (unsigned)x[(lane + 64 * k) * BATCH + b];
    }
    #pragma unroll
    for (int k = 0; k < 4; ++k)
        if (k < ntok) w[k] = W[tok[k]];    // dependent on tok, still 4-way ILP

    const float tail = b_lut[0] + bias[0];

    // Clear the table: 1024 words / 64 lanes = 4 uint4 per lane.
    uint4* htv = (uint4*)ht;
    #pragma unroll
    for (int k = 0; k < 4; ++k)
        htv[lane + 64 * k] = make_uint4(EMPTY, EMPTY, EMPTY, EMPTY);
    // Same-wave DS ops execute in issue order; no barrier needed before CAS.

    float contrib = 0.0f;
    #pragma unroll
    for (int k = 0; k < 4; ++k) {
        if (k >= ntok) continue;
        unsigned h = (tok[k] * 2654435761u) >> 22;   // top 10 bits
        for (;;) {
            unsigned old = atomicCAS(&ht[h], EMPTY, tok[k]);
            if (old == EMPTY) { contrib += w[k]; break; }  // first occurrence
            if (old == tok[k]) break;                      // duplicate
            h = (h + 1) & (HASH_SIZE - 1);
        }
    }

    // Single-wave shuffle reduction; lane 0 writes the result.
    for (int off = 32; off > 0; off >>= 1)
        contrib += __shfl_down(contrib, off, 64);

    if (lane == 0) out[b] = contrib + tail;
}

extern "C" void kernel_launch(void* const* d_in, const int* in_sizes, int n_in,
                              void* d_out, int out_size, void* d_ws, size_t ws_size,
                              hipStream_t stream) {
    const int*   x     = (const int*)d_in[0];
    const float* W     = (const float*)d_in[1];
    const float* b_lut = (const float*)d_in[2];
    const float* bias  = (const float*)d_in[3];
    float*       out   = (float*)d_out;

    LR2_kernel<<<BATCH, 64, 0, stream>>>(x, W, b_lut, bias, out);
}